// Round 1
// baseline (273.749 us; speedup 1.0000x reference)
//
#include <hip/hip_runtime.h>
#include <cstddef>

#define T_STEPS 128
#define D_IN    57
#define HDIM    64
#define ODIM    7
#define FAN     121   // D_IN + HDIM

// One wave (64 lanes) per sequence. Lane i owns hidden element i and keeps
// W_i2h row i (121 floats) resident in VGPRs for all 128 timesteps.
// h is broadcast lane->all via a 64-float LDS buffer (uniform ds_read_b128
// broadcasts, conflict-free). x_t is read as wave-uniform scalar loads
// (VMEM pipe, L1-hot after first touch of the 29 KB/seq stream).
__global__ __launch_bounds__(64, 3) void rnn_scan_kernel(
    const float* __restrict__ x,
    const float* __restrict__ W_i2h,
    const float* __restrict__ b_i2h,
    const float* __restrict__ W_i2o,
    const float* __restrict__ b_i2o,
    float* __restrict__ out,
    int B)
{
    const int lane = threadIdx.x;   // 0..63
    const int seq  = blockIdx.x;
    if (seq >= B) return;

    // Per-lane weight row: W_i2h[lane][0..120]
    float wr[FAN];
#pragma unroll
    for (int k = 0; k < FAN; ++k) wr[k] = W_i2h[lane * FAN + k];
    const float bi = b_i2h[lane];

    __shared__ __align__(16) float hs[HDIM];

    const float* __restrict__ xb = x + (size_t)seq * T_STEPS * D_IN;

    float h = 0.0f;      // current hidden (element `lane`)
    float hpre = 0.0f;   // hidden ENTERING the last valid step (ref: out_t uses h_{t-1})
    int tlast = -1;

    for (int t = 0; t < T_STEPS; ++t) {
        const float* __restrict__ xt = xb + (size_t)t * D_IN;

        hs[lane] = h;
        __syncthreads();   // 1 wave/block: near-free; orders LDS write->read

        float a0 = bi, a1 = 0.0f, a2 = 0.0f, a3 = 0.0f;
        const float x0 = xt[0];

        // x contribution: wave-uniform broadcast loads, chunked to bound
        // live-range growth of hoisted loads.
#pragma unroll
        for (int k = 0; k < 56; k += 4) {
            float v0 = xt[k + 0], v1 = xt[k + 1], v2 = xt[k + 2], v3 = xt[k + 3];
            a0 += wr[k + 0] * v0;
            a1 += wr[k + 1] * v1;
            a2 += wr[k + 2] * v2;
            a3 += wr[k + 3] * v3;
        }
        a0 += wr[56] * xt[56];

        // h contribution: uniform-address float4 broadcasts from LDS
        const float4* __restrict__ hv = reinterpret_cast<const float4*>(hs);
#pragma unroll
        for (int j = 0; j < 16; ++j) {
            float4 hh = hv[j];
            a0 += wr[57 + 4 * j + 0] * hh.x;
            a1 += wr[57 + 4 * j + 1] * hh.y;
            a2 += wr[57 + 4 * j + 2] * hh.z;
            a3 += wr[57 + 4 * j + 3] * hh.w;
        }
        float nh = (a0 + a1) + (a2 + a3);

        const bool valid = (x0 != -1.0f);   // wave-uniform
        hpre  = valid ? h  : hpre;          // save h BEFORE update (order matters)
        h     = valid ? nh : h;
        tlast = valid ? t  : tlast;
        __syncthreads();
    }

    float* __restrict__ outp = out + (size_t)seq * ODIM;

    if (tlast < 0) {
        // no valid step: reference returns the zero init
        if (lane < ODIM) outp[lane] = 0.0f;
        return;
    }

    // Final output projection + log_softmax, once per sequence.
    // logits[o] = sum_k Wo[o][k]*x_tlast[k] + sum_j Wo[o][57+j]*hpre[j] + bo[o]
    float xk = 0.0f;
    if (lane < D_IN) xk = xb[(size_t)tlast * D_IN + lane];

    float lg[ODIM];
#pragma unroll
    for (int o = 0; o < ODIM; ++o) {
        float wx = (lane < D_IN) ? W_i2o[o * FAN + lane] : 0.0f;
        float wh = W_i2o[o * FAN + D_IN + lane];
        float c  = wx * xk + wh * hpre;
#pragma unroll
        for (int d = 32; d >= 1; d >>= 1) c += __shfl_xor(c, d, 64);
        lg[o] = c + b_i2o[o];   // same value on all lanes
    }

    float m = lg[0];
#pragma unroll
    for (int o = 1; o < ODIM; ++o) m = fmaxf(m, lg[o]);
    float s = 0.0f;
#pragma unroll
    for (int o = 0; o < ODIM; ++o) s += __expf(lg[o] - m);
    const float lse = m + logf(s);

    if (lane == 0) {
#pragma unroll
        for (int o = 0; o < ODIM; ++o) outp[o] = lg[o] - lse;
    }
}

extern "C" void kernel_launch(void* const* d_in, const int* in_sizes, int n_in,
                              void* d_out, int out_size, void* d_ws, size_t ws_size,
                              hipStream_t stream)
{
    const float* x     = (const float*)d_in[0];
    const float* W_i2h = (const float*)d_in[1];
    const float* b_i2h = (const float*)d_in[2];
    const float* W_i2o = (const float*)d_in[3];
    const float* b_i2o = (const float*)d_in[4];
    float* out = (float*)d_out;

    const int B = in_sizes[0] / (T_STEPS * D_IN);

    dim3 grid(B), block(64);
    hipLaunchKernelGGL(rnn_scan_kernel, grid, block, 0, stream,
                       x, W_i2h, b_i2h, W_i2o, b_i2o, out, B);
}

// Round 3
// 115.927 us; speedup vs baseline: 2.3614x; 2.3614x over previous
//
#include <hip/hip_runtime.h>
#include <cstddef>

#define T_STEPS 128
#define D_IN    57
#define HDIM    64
#define ODIM    7
#define FAN     121
#define SEQ_PER_BLK 16

typedef __attribute__((ext_vector_type(8))) short    short8;
typedef __attribute__((ext_vector_type(4))) float    f32x4;
typedef __attribute__((ext_vector_type(4))) unsigned uint4v;
typedef __attribute__((ext_vector_type(2))) unsigned uint2v;

#define MFMA(a, b, c) __builtin_amdgcn_mfma_f32_16x16x32_bf16((a), (b), (c), 0, 0, 0)

union FragU { short8 s8; unsigned u[4]; uint4v u4; };

__device__ inline unsigned short f2bf(float f) {
    __bf16 h = (__bf16)f;
    return __builtin_bit_cast(unsigned short, h);
}
__device__ inline unsigned pk2(float lo, float hi) {
    return ((unsigned)f2bf(hi) << 16) | (unsigned)f2bf(lo);
}
// LDS bank-conflict swizzle: toggle byte bits 4..6 by seq (byte bits 7..9).
// Involutive; applied identically on write and read; keeps 16B alignment.
__device__ inline unsigned swz(unsigned b) {
    return b ^ (((b >> 7) & 7u) << 4);
}

// Weight fragment (A operand, row = W-row): slot (q,d,half) -> k = kbase+2d+half.
__device__ inline short8 wfragX(const float* Wr, int kbase) {   // x part, zero for k>=D_IN
    FragU f;
#pragma unroll
    for (int d = 0; d < 4; ++d) {
        int k0 = kbase + 2 * d, k1 = k0 + 1;
        float a = (k0 < D_IN) ? Wr[k0] : 0.0f;
        float b = (k1 < D_IN) ? Wr[k1] : 0.0f;
        f.u[d] = pk2(a, b);
    }
    return f.s8;
}
__device__ inline short8 wfragH(const float* Wr, int kbase) {   // h part, full 64
    FragU f;
#pragma unroll
    for (int d = 0; d < 4; ++d) {
        int k0 = kbase + 2 * d;
        f.u[d] = pk2(Wr[k0], Wr[k0 + 1]);
    }
    return f.s8;
}
__device__ inline short8 xfrag(const float* r) {
    FragU f;
#pragma unroll
    for (int d = 0; d < 4; ++d) f.u[d] = pk2(r[2 * d], r[2 * d + 1]);
    return f.s8;
}

struct XR { float a[8]; float b[8]; };

// Per-lane x loads for the B operand: lane (q,st) serves seq st, k-slots
// a: k = q*8 + 0..7, b: k = 32 + q*8 + 0..7 (q==3: only k=56 real).
__device__ inline void loadx(XR& r, const float* xrow, int t, int q) {
    const float* p = xrow + t * D_IN;
#pragma unroll
    for (int i = 0; i < 8; ++i) r.a[i] = p[q * 8 + i];
    if (q == 3) {
        r.b[0] = p[56];
#pragma unroll
        for (int i = 1; i < 8; ++i) r.b[i] = 0.0f;
    } else {
#pragma unroll
        for (int i = 0; i < 8; ++i) r.b[i] = p[32 + q * 8 + i];
    }
}

__global__ __launch_bounds__(64, 1) void rnn_mfma_kernel(
    const float* __restrict__ x,
    const float* __restrict__ W_i2h,
    const float* __restrict__ b_i2h,
    const float* __restrict__ W_i2o,
    const float* __restrict__ b_i2o,
    float* __restrict__ out,
    int B)
{
    const int lane = threadIdx.x;
    const int st   = lane & 15;     // B col = seq within tile; A row = W row within tile
    const int q    = lane >> 4;     // K quarter
    const int seq0 = blockIdx.x * SEQ_PER_BLK;

    // H LDS (seq-major, swizzled): elem(s, k) = s*64 + k  (bf16), s=seq, k=hid
    __shared__ __align__(16) unsigned short Hs[SEQ_PER_BLK * HDIM];
    __shared__ __align__(16) float Hp[SEQ_PER_BLK][68];   // padded f32 h_pre for epilogue
    __shared__ int   Tl[SEQ_PER_BLK];
    __shared__ float Lg[SEQ_PER_BLK][8];

    char* HsB = (char*)Hs;

    // zero H (h_0 = 0): 2048 B, 32 B/lane
    {
        uint4v z = 0;
        *(uint4v*)(HsB + lane * 32)      = z;
        *(uint4v*)(HsB + lane * 32 + 16) = z;
    }

    // Resident weights: A-frags, tile n = W rows 16n..16n+15 (this lane: row 16n+st)
    short8 wx[4][2], wh[4][2];
    f32x4  biasv[4];
#pragma unroll
    for (int n = 0; n < 4; ++n) {
        const float* wr_ = W_i2h + (size_t)(16 * n + st) * FAN;
        wx[n][0] = wfragX(wr_, q * 8);
        wx[n][1] = wfragX(wr_, 32 + q * 8);
        wh[n][0] = wfragH(wr_ + D_IN, q * 8);
        wh[n][1] = wfragH(wr_ + D_IN, 32 + q * 8);
#pragma unroll
        for (int j = 0; j < 4; ++j) biasv[n][j] = b_i2h[16 * n + 4 * q + j];
    }

    int seqL = seq0 + st; if (seqL >= B) seqL = B - 1;
    const float* xrow = x + (size_t)seqL * T_STEPS * D_IN;

    // C/D state: lane (q,st) holds h[hid = 16n + 4q + j][seq = st]
    f32x4 hcur[4], hpre[4];
#pragma unroll
    for (int n = 0; n < 4; ++n) { hcur[n] = 0.0f; hpre[n] = 0.0f; }
    int tl = -1;

    // LDS addresses (bytes, swizzled)
    const unsigned rb0 = swz((unsigned)(128 * st + 16 * q));        // k = 8q+0..7
    const unsigned rb1 = swz((unsigned)(128 * st + 64 + 16 * q));   // k = 32+8q+0..7
    unsigned wb[4];
#pragma unroll
    for (int n = 0; n < 4; ++n)
        wb[n] = swz((unsigned)(128 * st + 32 * n + 8 * q));          // k = 16n+4q+0..3

    XR r0, r1, r2, r3;
    loadx(r0, xrow, 0, q);
    loadx(r1, xrow, 1, q);
    loadx(r2, xrow, 2, q);
    loadx(r3, xrow, 3, q);

    auto STEP = [&](XR& cur, int t) {
        // 1. previous H -> B_h fragments (plain swizzled ds_read_b128)
        FragU bh0, bh1;
        bh0.u4 = *(const uint4v*)(HsB + rb0);
        bh1.u4 = *(const uint4v*)(HsB + rb1);
        // 2. x -> B_x fragments; capture x0 before the prefetch overwrites cur
        short8 bx0 = xfrag(cur.a);
        short8 bx1 = xfrag(cur.b);
        float  x0l = cur.a[0];
        // 3. prefetch x for t+4 into the just-consumed slot
        int tn = t + 4; if (tn > T_STEPS - 1) tn = T_STEPS - 1;
        loadx(cur, xrow, tn, q);
        // 4. C[hid][seq] = W · [x|h] + bias
        f32x4 acc[4];
#pragma unroll
        for (int n = 0; n < 4; ++n) {
            f32x4 c = biasv[n];
            c = MFMA(wx[n][0], bx0, c);
            c = MFMA(wx[n][1], bx1, c);
            c = MFMA(wh[n][0], bh0.s8, c);
            c = MFMA(wh[n][1], bh1.s8, c);
            acc[n] = c;
        }
        // 5. validity of this lane's seq (wavewide pull from lane st, which holds x_t[0])
        bool v = (__shfl(x0l, st, 64) != -1.0f);
        // 6. state update (hpre = h entering the last valid step)
#pragma unroll
        for (int n = 0; n < 4; ++n) {
#pragma unroll
            for (int j = 0; j < 4; ++j) {
                float o = hcur[n][j];
                hpre[n][j] = v ? o : hpre[n][j];
                hcur[n][j] = v ? acc[n][j] : o;
            }
        }
        tl = v ? t : tl;
        // 7. write H_t (4x ds_write_b64, hid-contiguous, swizzled)
#pragma unroll
        for (int n = 0; n < 4; ++n) {
            uint2v w;
            w[0] = pk2(hcur[n][0], hcur[n][1]);
            w[1] = pk2(hcur[n][2], hcur[n][3]);
            *(uint2v*)(HsB + wb[n]) = w;
        }
        // keep compiler from reordering next step's LDS reads above these writes
        asm volatile("" ::: "memory");
    };

    for (int tb = 0; tb < T_STEPS; tb += 4) {
        STEP(r0, tb + 0);
        STEP(r1, tb + 1);
        STEP(r2, tb + 2);
        STEP(r3, tb + 3);
    }

    // ---- epilogue ----
#pragma unroll
    for (int n = 0; n < 4; ++n)
        *(f32x4*)&Hp[st][16 * n + 4 * q] = hpre[n];
    if (lane < SEQ_PER_BLK) Tl[st] = tl;   // lanes 0..15 are q==0; same tl across q
    __syncthreads();

    {
        int s = lane >> 2, p = lane & 3;
        int seq = seq0 + s;
        int t_l = Tl[s];
        float lgo0 = 0.0f, lgo1 = 0.0f;
        if (seq < B && t_l >= 0) {
            const float* xr = x + ((size_t)seq * T_STEPS + t_l) * D_IN;
            {
                const float* wo = W_i2o + p * FAN;
                float a = b_i2o[p];
                for (int k = 0; k < D_IN; ++k) a += xr[k] * wo[k];
                for (int k = 0; k < HDIM; ++k) a += Hp[s][k] * wo[D_IN + k];
                lgo0 = a;
            }
            if (p < 3) {
                const float* wo = W_i2o + (p + 4) * FAN;
                float a = b_i2o[p + 4];
                for (int k = 0; k < D_IN; ++k) a += xr[k] * wo[k];
                for (int k = 0; k < HDIM; ++k) a += Hp[s][k] * wo[D_IN + k];
                lgo1 = a;
            }
        }
        Lg[s][p] = lgo0;
        if (p < 3) Lg[s][p + 4] = lgo1;
    }
    __syncthreads();

    if (lane < SEQ_PER_BLK) {
        int s = lane, seq = seq0 + s;
        if (seq < B) {
            float* op = out + (size_t)seq * ODIM;
            if (Tl[s] < 0) {
#pragma unroll
                for (int o = 0; o < ODIM; ++o) op[o] = 0.0f;
            } else {
                float m = Lg[s][0];
#pragma unroll
                for (int o = 1; o < ODIM; ++o) m = fmaxf(m, Lg[s][o]);
                float sum = 0.0f;
#pragma unroll
                for (int o = 0; o < ODIM; ++o) sum += expf(Lg[s][o] - m);
                float lse = m + logf(sum);
#pragma unroll
                for (int o = 0; o < ODIM; ++o) op[o] = Lg[s][o] - lse;
            }
        }
    }
}

extern "C" void kernel_launch(void* const* d_in, const int* in_sizes, int n_in,
                              void* d_out, int out_size, void* d_ws, size_t ws_size,
                              hipStream_t stream)
{
    const float* x     = (const float*)d_in[0];
    const float* W_i2h = (const float*)d_in[1];
    const float* b_i2h = (const float*)d_in[2];
    const float* W_i2o = (const float*)d_in[3];
    const float* b_i2o = (const float*)d_in[4];
    float* out = (float*)d_out;

    const int B = in_sizes[0] / (T_STEPS * D_IN);
    const int nblk = (B + SEQ_PER_BLK - 1) / SEQ_PER_BLK;

    dim3 grid(nblk), block(64);
    hipLaunchKernelGGL(rnn_mfma_kernel, grid, block, 0, stream,
                       x, W_i2h, b_i2h, W_i2o, b_i2o, out, B);
}

// Round 4
// 101.322 us; speedup vs baseline: 2.7018x; 1.1442x over previous
//
#include <hip/hip_runtime.h>
#include <cstddef>

#define T_STEPS 128
#define D_IN    57
#define HDIM    64
#define ODIM    7
#define FAN     121
#define SEQ_PER_BLK 16

typedef __attribute__((ext_vector_type(8))) short    short8;
typedef __attribute__((ext_vector_type(4))) float    f32x4;
typedef __attribute__((ext_vector_type(4))) unsigned uint4v;
typedef __attribute__((ext_vector_type(2))) unsigned uint2v;

#define MFMA(a, b, c) __builtin_amdgcn_mfma_f32_16x16x32_bf16((a), (b), (c), 0, 0, 0)
// DS ops may not cross (keeps write(t) -> read(t+1) LDS order); everything else may.
#define DS_FENCE() __builtin_amdgcn_sched_barrier(0x7F)

union FragU { short8 s8; unsigned u[4]; uint4v u4; };

__device__ inline unsigned short f2bf(float f) {
    __bf16 h = (__bf16)f;
    return __builtin_bit_cast(unsigned short, h);
}
__device__ inline unsigned pk2(float lo, float hi) {
    return ((unsigned)f2bf(hi) << 16) | (unsigned)f2bf(lo);
}
// Involutive LDS swizzle, applied on both write and read; keeps 16B alignment.
__device__ inline unsigned swz(unsigned b) {
    return b ^ (((b >> 7) & 7u) << 4);
}

__device__ inline short8 wfragX(const float* Wr, int kbase) {   // x part, zero pad k>=D_IN
    FragU f;
#pragma unroll
    for (int d = 0; d < 4; ++d) {
        int k0 = kbase + 2 * d, k1 = k0 + 1;
        float a = (k0 < D_IN) ? Wr[k0] : 0.0f;
        float b = (k1 < D_IN) ? Wr[k1] : 0.0f;
        f.u[d] = pk2(a, b);
    }
    return f.s8;
}
__device__ inline short8 wfragH(const float* Wr, int kbase) {   // h part, full 64
    FragU f;
#pragma unroll
    for (int d = 0; d < 4; ++d) {
        int k0 = kbase + 2 * d;
        f.u[d] = pk2(Wr[k0], Wr[k0 + 1]);
    }
    return f.s8;
}
__device__ inline short8 xfrag(const float* r) {
    FragU f;
#pragma unroll
    for (int d = 0; d < 4; ++d) f.u[d] = pk2(r[2 * d], r[2 * d + 1]);
    return f.s8;
}

struct XR { float a[8]; float b[8]; };

__device__ inline void loadx(XR& r, const float* xrow, int t, int q) {
    const float* p = xrow + t * D_IN;
#pragma unroll
    for (int i = 0; i < 8; ++i) r.a[i] = p[q * 8 + i];
    if (q == 3) {
        r.b[0] = p[56];
#pragma unroll
        for (int i = 1; i < 8; ++i) r.b[i] = 0.0f;
    } else {
#pragma unroll
        for (int i = 0; i < 8; ++i) r.b[i] = p[32 + q * 8 + i];
    }
}

__global__ __launch_bounds__(64, 1) void rnn_mfma_kernel(
    const float* __restrict__ x,
    const float* __restrict__ W_i2h,
    const float* __restrict__ b_i2h,
    const float* __restrict__ W_i2o,
    const float* __restrict__ b_i2o,
    float* __restrict__ out,
    int B)
{
    const int lane = threadIdx.x;
    const int st   = lane & 15;     // B col = seq within tile; A row = W row within tile
    const int q    = lane >> 4;     // K quarter
    const int seq0 = blockIdx.x * SEQ_PER_BLK;

    __shared__ __align__(16) unsigned short Hs[SEQ_PER_BLK * HDIM];  // h_t, bf16, seq-major
    __shared__ __align__(16) float Hp[SEQ_PER_BLK][68];
    __shared__ int      Tl[SEQ_PER_BLK];
    __shared__ float    Lg[SEQ_PER_BLK][8];
    __shared__ unsigned Ms[SEQ_PER_BLK][4];

    char* HsB = (char*)Hs;

    // zero h_0
    {
        uint4v z = 0;
        *(uint4v*)(HsB + lane * 32)      = z;
        *(uint4v*)(HsB + lane * 32 + 16) = z;
    }

    // Resident weights (A-frags, this lane: W row 16n+st, K quarter q)
    short8 wx[4][2], wh[4][2];
    f32x4  biasv[4];
#pragma unroll
    for (int n = 0; n < 4; ++n) {
        const float* wr_ = W_i2h + (size_t)(16 * n + st) * FAN;
        wx[n][0] = wfragX(wr_, q * 8);
        wx[n][1] = wfragX(wr_, 32 + q * 8);
        wh[n][0] = wfragH(wr_ + D_IN, q * 8);
        wh[n][1] = wfragH(wr_ + D_IN, 32 + q * 8);
#pragma unroll
        for (int j = 0; j < 4; ++j) biasv[n][j] = b_i2h[16 * n + 4 * q + j];
    }

    int seqL = seq0 + st; if (seqL >= B) seqL = B - 1;
    const float* xrow = x + (size_t)seqL * T_STEPS * D_IN;

    // Validity masks: lane (q,st) scans t = 32q..32q+31 of seq st, exchange via LDS.
    {
        unsigned m = 0;
        const float* xq = xrow + (size_t)(q * 32) * D_IN;
#pragma unroll
        for (int i = 0; i < 32; ++i)
            m |= ((xq[(size_t)i * D_IN] != -1.0f) ? 1u : 0u) << i;
        Ms[st][q] = m;
    }
    __syncthreads();   // orders h_0 zero + Ms for the whole wave
    const unsigned mk0 = Ms[st][0], mk1 = Ms[st][1];
    const unsigned mk2 = Ms[st][2], mk3 = Ms[st][3];
    const bool allv = __all((int)((mk0 & mk1 & mk2 & mk3) == 0xFFFFFFFFu));

    // C/D state: lane (q,st) holds h[hid = 16n+4q+j][seq = st]
    f32x4 hcur[4], hpre[4];
#pragma unroll
    for (int n = 0; n < 4; ++n) { hcur[n] = 0.0f; hpre[n] = 0.0f; }

    const unsigned rb0 = swz((unsigned)(128 * st + 16 * q));
    const unsigned rb1 = swz((unsigned)(128 * st + 64 + 16 * q));
    unsigned wb[4];
#pragma unroll
    for (int n = 0; n < 4; ++n)
        wb[n] = swz((unsigned)(128 * st + 32 * n + 8 * q));

    XR r0, r1, r2, r3, r4, r5, r6, r7;
    loadx(r0, xrow, 0, q); loadx(r1, xrow, 1, q);
    loadx(r2, xrow, 2, q); loadx(r3, xrow, 3, q);
    loadx(r4, xrow, 4, q); loadx(r5, xrow, 5, q);
    loadx(r6, xrow, 6, q); loadx(r7, xrow, 7, q);

    // Shared step core: returns acc (pre-select), prefetches t+8.
    auto CORE = [&](XR& cur, int t, f32x4* acc) {
        FragU bh0, bh1;
        bh0.u4 = *(const uint4v*)(HsB + rb0);
        bh1.u4 = *(const uint4v*)(HsB + rb1);
        short8 bx0 = xfrag(cur.a);
        short8 bx1 = xfrag(cur.b);
        int tn = t + 8; if (tn > T_STEPS - 1) tn = T_STEPS - 1;
        loadx(cur, xrow, tn, q);
#pragma unroll
        for (int n = 0; n < 4; ++n) {
            f32x4 c = biasv[n];
            c = MFMA(wx[n][0], bx0, c);
            c = MFMA(wx[n][1], bx1, c);
            c = MFMA(wh[n][0], bh0.s8, c);
            c = MFMA(wh[n][1], bh1.s8, c);
            acc[n] = c;
        }
    };
    auto WRITEH = [&]() {
#pragma unroll
        for (int n = 0; n < 4; ++n) {
            uint2v w;
            w[0] = pk2(hcur[n][0], hcur[n][1]);
            w[1] = pk2(hcur[n][2], hcur[n][3]);
            *(uint2v*)(HsB + wb[n]) = w;
        }
        DS_FENCE();
    };
    auto STEPF = [&](XR& cur, int t) {            // all-valid fast path
        f32x4 acc[4];
        CORE(cur, t, acc);
#pragma unroll
        for (int n = 0; n < 4; ++n) hcur[n] = acc[n];
        WRITEH();
    };
    auto STEPG = [&](XR& cur, int t, unsigned vbit) {   // general path
        f32x4 acc[4];
        CORE(cur, t, acc);
        bool v = vbit != 0;
#pragma unroll
        for (int n = 0; n < 4; ++n) {
#pragma unroll
            for (int j = 0; j < 4; ++j) {
                float o = hcur[n][j];
                hpre[n][j] = v ? o : hpre[n][j];
                hcur[n][j] = v ? acc[n][j] : o;
            }
        }
        WRITEH();
    };

    int tlv = -1;

    if (allv) {
        for (int tb = 0; tb < T_STEPS - 8; tb += 8) {
            STEPF(r0, tb + 0); STEPF(r1, tb + 1); STEPF(r2, tb + 2); STEPF(r3, tb + 3);
            STEPF(r4, tb + 4); STEPF(r5, tb + 5); STEPF(r6, tb + 6); STEPF(r7, tb + 7);
        }
        STEPF(r0, 120); STEPF(r1, 121); STEPF(r2, 122); STEPF(r3, 123);
        STEPF(r4, 124); STEPF(r5, 125); STEPF(r6, 126);
#pragma unroll
        for (int n = 0; n < 4; ++n) hpre[n] = hcur[n];   // h entering t=127
        STEPF(r7, 127);
        tlv = 127;
    } else {
        const unsigned mks[4] = { mk0, mk1, mk2, mk3 };
#pragma unroll 1
        for (int jb = 0; jb < 4; ++jb) {
            unsigned mw = mks[jb];
            int t0 = jb * 32;
#pragma unroll 1
            for (int i = 0; i < 32; i += 8) {
                STEPG(r0, t0 + i + 0, mw & 1u);        mw >>= 1;
                STEPG(r1, t0 + i + 1, mw & 1u);        mw >>= 1;
                STEPG(r2, t0 + i + 2, mw & 1u);        mw >>= 1;
                STEPG(r3, t0 + i + 3, mw & 1u);        mw >>= 1;
                STEPG(r4, t0 + i + 4, mw & 1u);        mw >>= 1;
                STEPG(r5, t0 + i + 5, mw & 1u);        mw >>= 1;
                STEPG(r6, t0 + i + 6, mw & 1u);        mw >>= 1;
                STEPG(r7, t0 + i + 7, mw & 1u);        mw >>= 1;
            }
        }
        if (mk3)      tlv = 127 - __builtin_clz(mk3);
        else if (mk2) tlv =  95 - __builtin_clz(mk2);
        else if (mk1) tlv =  63 - __builtin_clz(mk1);
        else if (mk0) tlv =  31 - __builtin_clz(mk0);
        else          tlv = -1;
    }

    // ---- epilogue ----
#pragma unroll
    for (int n = 0; n < 4; ++n)
        *(f32x4*)&Hp[st][16 * n + 4 * q] = hpre[n];
    if (lane < SEQ_PER_BLK) Tl[st] = tlv;
    __syncthreads();

    {
        int s = lane >> 2, p = lane & 3;
        int seq = seq0 + s;
        int t_l = Tl[s];
        float lgo0 = 0.0f, lgo1 = 0.0f;
        if (seq < B && t_l >= 0) {
            const float* xr = x + ((size_t)seq * T_STEPS + t_l) * D_IN;
            {
                const float* wo = W_i2o + p * FAN;
                float a = b_i2o[p];
                for (int k = 0; k < D_IN; ++k) a += xr[k] * wo[k];
                for (int k = 0; k < HDIM; ++k) a += Hp[s][k] * wo[D_IN + k];
                lgo0 = a;
            }
            if (p < 3) {
                const float* wo = W_i2o + (p + 4) * FAN;
                float a = b_i2o[p + 4];
                for (int k = 0; k < D_IN; ++k) a += xr[k] * wo[k];
                for (int k = 0; k < HDIM; ++k) a += Hp[s][k] * wo[D_IN + k];
                lgo1 = a;
            }
        }
        Lg[s][p] = lgo0;
        if (p < 3) Lg[s][p + 4] = lgo1;
    }
    __syncthreads();

    if (lane < SEQ_PER_BLK) {
        int s = lane, seq = seq0 + s;
        if (seq < B) {
            float* op = out + (size_t)seq * ODIM;
            if (Tl[s] < 0) {
#pragma unroll
                for (int o = 0; o < ODIM; ++o) op[o] = 0.0f;
            } else {
                float m = Lg[s][0];
#pragma unroll
                for (int o = 1; o < ODIM; ++o) m = fmaxf(m, Lg[s][o]);
                float sum = 0.0f;
#pragma unroll
                for (int o = 0; o < ODIM; ++o) sum += expf(Lg[s][o] - m);
                float lse = m + logf(sum);
#pragma unroll
                for (int o = 0; o < ODIM; ++o) op[o] = Lg[s][o] - lse;
            }
        }
    }
}

extern "C" void kernel_launch(void* const* d_in, const int* in_sizes, int n_in,
                              void* d_out, int out_size, void* d_ws, size_t ws_size,
                              hipStream_t stream)
{
    const float* x     = (const float*)d_in[0];
    const float* W_i2h = (const float*)d_in[1];
    const float* b_i2h = (const float*)d_in[2];
    const float* W_i2o = (const float*)d_in[3];
    const float* b_i2o = (const float*)d_in[4];
    float* out = (float*)d_out;

    const int B = in_sizes[0] / (T_STEPS * D_IN);
    const int nblk = (B + SEQ_PER_BLK - 1) / SEQ_PER_BLK;

    dim3 grid(nblk), block(64);
    hipLaunchKernelGGL(rnn_mfma_kernel, grid, block, 0, stream,
                       x, W_i2h, b_i2h, W_i2o, b_i2o, out, B);
}

// Round 5
// 100.202 us; speedup vs baseline: 2.7320x; 1.0112x over previous
//
#include <hip/hip_runtime.h>
#include <cstddef>

#define T_STEPS 128
#define D_IN    57
#define HDIM    64
#define ODIM    7
#define FAN     121
#define SEQ_PER_BLK 16

typedef __attribute__((ext_vector_type(8))) short    short8;
typedef __attribute__((ext_vector_type(4))) float    f32x4;
typedef __attribute__((ext_vector_type(4))) unsigned uint4v;
typedef __attribute__((ext_vector_type(2))) unsigned uint2v;

#define MFMA(a, b, c) __builtin_amdgcn_mfma_f32_16x16x32_bf16((a), (b), (c), 0, 0, 0)
// DS ops may not cross (keeps write(t) -> read(t+1) LDS order); everything else may.
#define DS_FENCE() __builtin_amdgcn_sched_barrier(0x7F)

union FragU { short8 s8; unsigned u[4]; uint4v u4; };

__device__ inline unsigned short f2bf(float f) {
    __bf16 h = (__bf16)f;
    return __builtin_bit_cast(unsigned short, h);
}
__device__ inline unsigned pk2(float lo, float hi) {
    return ((unsigned)f2bf(hi) << 16) | (unsigned)f2bf(lo);
}
// Involutive LDS swizzle, applied on both write and read; keeps 16B alignment.
__device__ inline unsigned swz(unsigned b) {
    return b ^ (((b >> 7) & 7u) << 4);
}

__device__ inline short8 wfragX(const float* Wr, int kbase) {   // x part, zero pad k>=D_IN
    FragU f;
#pragma unroll
    for (int d = 0; d < 4; ++d) {
        int k0 = kbase + 2 * d, k1 = k0 + 1;
        float a = (k0 < D_IN) ? Wr[k0] : 0.0f;
        float b = (k1 < D_IN) ? Wr[k1] : 0.0f;
        f.u[d] = pk2(a, b);
    }
    return f.s8;
}
__device__ inline short8 wfragH(const float* Wr, int kbase) {   // h part, full 64
    FragU f;
#pragma unroll
    for (int d = 0; d < 4; ++d) {
        int k0 = kbase + 2 * d;
        f.u[d] = pk2(Wr[k0], Wr[k0 + 1]);
    }
    return f.s8;
}
__device__ inline short8 xfrag(const float* r) {
    FragU f;
#pragma unroll
    for (int d = 0; d < 4; ++d) f.u[d] = pk2(r[2 * d], r[2 * d + 1]);
    return f.s8;
}

struct XR { float a[8]; float b[8]; };

__device__ inline void loadx(XR& r, const float* xrow, int t, int q) {
    const float* p = xrow + t * D_IN;
#pragma unroll
    for (int i = 0; i < 8; ++i) r.a[i] = p[q * 8 + i];
    if (q == 3) {
        r.b[0] = p[56];
#pragma unroll
        for (int i = 1; i < 8; ++i) r.b[i] = 0.0f;
    } else {
#pragma unroll
        for (int i = 0; i < 8; ++i) r.b[i] = p[32 + q * 8 + i];
    }
}

__global__ __launch_bounds__(64, 1) void rnn_mfma_kernel(
    const float* __restrict__ x,
    const float* __restrict__ W_i2h,
    const float* __restrict__ b_i2h,
    const float* __restrict__ W_i2o,
    const float* __restrict__ b_i2o,
    float* __restrict__ out,
    int B)
{
    const int lane = threadIdx.x;
    const int st   = lane & 15;     // B col = seq within tile; A row = W row within tile
    const int q    = lane >> 4;     // K quarter
    const int seq0 = blockIdx.x * SEQ_PER_BLK;

    __shared__ __align__(16) unsigned short Hs[SEQ_PER_BLK * HDIM];  // h_t, bf16, seq-major
    __shared__ __align__(16) float Hp[SEQ_PER_BLK][68];
    __shared__ int      Tl[SEQ_PER_BLK];
    __shared__ float    Lg[SEQ_PER_BLK][8];
    __shared__ unsigned Ms[SEQ_PER_BLK][4];

    char* HsB = (char*)Hs;

    // zero h_0
    {
        uint4v z = 0;
        *(uint4v*)(HsB + lane * 32)      = z;
        *(uint4v*)(HsB + lane * 32 + 16) = z;
    }

    // Resident weights (A-frags, this lane: W row 16n+st, K quarter q)
    short8 wx[4][2], wh[4][2];
    f32x4  biasv[4];
#pragma unroll
    for (int n = 0; n < 4; ++n) {
        const float* wr_ = W_i2h + (size_t)(16 * n + st) * FAN;
        wx[n][0] = wfragX(wr_, q * 8);
        wx[n][1] = wfragX(wr_, 32 + q * 8);
        wh[n][0] = wfragH(wr_ + D_IN, q * 8);
        wh[n][1] = wfragH(wr_ + D_IN, 32 + q * 8);
#pragma unroll
        for (int j = 0; j < 4; ++j) biasv[n][j] = b_i2h[16 * n + 4 * q + j];
    }

    int seqL = seq0 + st; if (seqL >= B) seqL = B - 1;
    const float* xrow = x + (size_t)seqL * T_STEPS * D_IN;

    // Validity masks: lane (q,st) scans t = 32q..32q+31 of seq st, exchange via LDS.
    {
        unsigned m = 0;
        const float* xq = xrow + (size_t)(q * 32) * D_IN;
#pragma unroll
        for (int i = 0; i < 32; ++i)
            m |= ((xq[(size_t)i * D_IN] != -1.0f) ? 1u : 0u) << i;
        Ms[st][q] = m;
    }
    __syncthreads();
    const unsigned mk0 = Ms[st][0], mk1 = Ms[st][1];
    const unsigned mk2 = Ms[st][2], mk3 = Ms[st][3];
    const bool allv = __all((int)((mk0 & mk1 & mk2 & mk3) == 0xFFFFFFFFu));

    // C/D state: lane (q,st) holds h[hid = 16n+4q+j][seq = st]
    f32x4 hcur[4], hpre[4];
#pragma unroll
    for (int n = 0; n < 4; ++n) { hcur[n] = 0.0f; hpre[n] = 0.0f; }

    const unsigned rb0 = swz((unsigned)(128 * st + 16 * q));
    const unsigned rb1 = swz((unsigned)(128 * st + 64 + 16 * q));
    unsigned wb[4];
#pragma unroll
    for (int n = 0; n < 4; ++n)
        wb[n] = swz((unsigned)(128 * st + 32 * n + 8 * q));

    // depth-4 x prefetch (64 VGPRs) -- fits without spilling
    XR r0, r1, r2, r3;
    loadx(r0, xrow, 0, q); loadx(r1, xrow, 1, q);
    loadx(r2, xrow, 2, q); loadx(r3, xrow, 3, q);

    auto CORE = [&](XR& cur, int t, f32x4* acc) {
        FragU bh0, bh1;
        bh0.u4 = *(const uint4v*)(HsB + rb0);
        bh1.u4 = *(const uint4v*)(HsB + rb1);
        short8 bx0 = xfrag(cur.a);
        short8 bx1 = xfrag(cur.b);
        int tn = t + 4; if (tn > T_STEPS - 1) tn = T_STEPS - 1;
        loadx(cur, xrow, tn, q);
#pragma unroll
        for (int n = 0; n < 4; ++n) {
            f32x4 c = biasv[n];
            c = MFMA(wx[n][0], bx0, c);
            c = MFMA(wx[n][1], bx1, c);
            c = MFMA(wh[n][0], bh0.s8, c);
            c = MFMA(wh[n][1], bh1.s8, c);
            acc[n] = c;
        }
    };
    auto WRITEH = [&]() {
#pragma unroll
        for (int n = 0; n < 4; ++n) {
            uint2v w;
            w[0] = pk2(hcur[n][0], hcur[n][1]);
            w[1] = pk2(hcur[n][2], hcur[n][3]);
            *(uint2v*)(HsB + wb[n]) = w;
        }
        DS_FENCE();
    };
    auto STEPF = [&](XR& cur, int t) {            // all-valid fast path
        f32x4 acc[4];
        CORE(cur, t, acc);
#pragma unroll
        for (int n = 0; n < 4; ++n) hcur[n] = acc[n];
        WRITEH();
    };
    auto STEPG = [&](XR& cur, int t, unsigned vbit) {   // general path
        f32x4 acc[4];
        CORE(cur, t, acc);
        bool v = vbit != 0;
#pragma unroll
        for (int n = 0; n < 4; ++n) {
#pragma unroll
            for (int j = 0; j < 4; ++j) {
                float o = hcur[n][j];
                hpre[n][j] = v ? o : hpre[n][j];
                hcur[n][j] = v ? acc[n][j] : o;
            }
        }
        WRITEH();
    };

    int tlv = -1;

    if (allv) {
        for (int tb = 0; tb < T_STEPS - 4; tb += 4) {
            STEPF(r0, tb + 0); STEPF(r1, tb + 1);
            STEPF(r2, tb + 2); STEPF(r3, tb + 3);
        }
        STEPF(r0, 124); STEPF(r1, 125); STEPF(r2, 126);
#pragma unroll
        for (int n = 0; n < 4; ++n) hpre[n] = hcur[n];   // h entering t=127
        STEPF(r3, 127);
        tlv = 127;
    } else {
        const unsigned mks[4] = { mk0, mk1, mk2, mk3 };
#pragma unroll 1
        for (int jb = 0; jb < 4; ++jb) {
            unsigned mw = mks[jb];
            int t0 = jb * 32;
#pragma unroll 1
            for (int i = 0; i < 32; i += 4) {
                STEPG(r0, t0 + i + 0, mw & 1u);  mw >>= 1;
                STEPG(r1, t0 + i + 1, mw & 1u);  mw >>= 1;
                STEPG(r2, t0 + i + 2, mw & 1u);  mw >>= 1;
                STEPG(r3, t0 + i + 3, mw & 1u);  mw >>= 1;
            }
        }
        if (mk3)      tlv = 127 - __builtin_clz(mk3);
        else if (mk2) tlv =  95 - __builtin_clz(mk2);
        else if (mk1) tlv =  63 - __builtin_clz(mk1);
        else if (mk0) tlv =  31 - __builtin_clz(mk0);
        else          tlv = -1;
    }

    // ---- epilogue ----
#pragma unroll
    for (int n = 0; n < 4; ++n)
        *(f32x4*)&Hp[st][16 * n + 4 * q] = hpre[n];
    if (lane < SEQ_PER_BLK) Tl[st] = tlv;
    __syncthreads();

    {
        int s = lane >> 2, p = lane & 3;
        int seq = seq0 + s;
        int t_l = Tl[s];
        float lgo0 = 0.0f, lgo1 = 0.0f;
        if (seq < B && t_l >= 0) {
            const float* xr = x + ((size_t)seq * T_STEPS + t_l) * D_IN;
            {
                const float* wo = W_i2o + p * FAN;
                float a = b_i2o[p];
                for (int k = 0; k < D_IN; ++k) a += xr[k] * wo[k];
                for (int k = 0; k < HDIM; ++k) a += Hp[s][k] * wo[D_IN + k];
                lgo0 = a;
            }
            if (p < 3) {
                const float* wo = W_i2o + (p + 4) * FAN;
                float a = b_i2o[p + 4];
                for (int k = 0; k < D_IN; ++k) a += xr[k] * wo[k];
                for (int k = 0; k < HDIM; ++k) a += Hp[s][k] * wo[D_IN + k];
                lgo1 = a;
            }
        }
        Lg[s][p] = lgo0;
        if (p < 3) Lg[s][p + 4] = lgo1;
    }
    __syncthreads();

    if (lane < SEQ_PER_BLK) {
        int s = lane, seq = seq0 + s;
        if (seq < B) {
            float* op = out + (size_t)seq * ODIM;
            if (Tl[s] < 0) {
#pragma unroll
                for (int o = 0; o < ODIM; ++o) op[o] = 0.0f;
            } else {
                float m = Lg[s][0];
#pragma unroll
                for (int o = 1; o < ODIM; ++o) m = fmaxf(m, Lg[s][o]);
                float sum = 0.0f;
#pragma unroll
                for (int o = 0; o < ODIM; ++o) sum += expf(Lg[s][o] - m);
                float lse = m + logf(sum);
#pragma unroll
                for (int o = 0; o < ODIM; ++o) op[o] = Lg[s][o] - lse;
            }
        }
    }
}

extern "C" void kernel_launch(void* const* d_in, const int* in_sizes, int n_in,
                              void* d_out, int out_size, void* d_ws, size_t ws_size,
                              hipStream_t stream)
{
    const float* x     = (const float*)d_in[0];
    const float* W_i2h = (const float*)d_in[1];
    const float* b_i2h = (const float*)d_in[2];
    const float* W_i2o = (const float*)d_in[3];
    const float* b_i2o = (const float*)d_in[4];
    float* out = (float*)d_out;

    const int B = in_sizes[0] / (T_STEPS * D_IN);
    const int nblk = (B + SEQ_PER_BLK - 1) / SEQ_PER_BLK;

    dim3 grid(nblk), block(64);
    hipLaunchKernelGGL(rnn_mfma_kernel, grid, block, 0, stream,
                       x, W_i2h, b_i2h, W_i2o, b_i2o, out, B);
}

// Round 6
// 80.233 us; speedup vs baseline: 3.4119x; 1.2489x over previous
//
#include <hip/hip_runtime.h>
#include <cstddef>
#include <cstdint>

#define T_STEPS 128
#define D_IN    57
#define HDIM    64
#define ODIM    7
#define FAN     121
#define SEQ_PER_BLK 16
#define XROW_B  (T_STEPS * D_IN * 4)   // 29184 bytes per sequence (divisible by 16)

typedef __attribute__((ext_vector_type(8))) short    short8;
typedef __attribute__((ext_vector_type(4))) float    f32x4;
typedef __attribute__((ext_vector_type(2))) float    f32x2;
typedef __attribute__((ext_vector_type(4))) unsigned uint4v;
typedef __attribute__((ext_vector_type(2))) unsigned uint2v;

#define MFMA(a,b,c) __builtin_amdgcn_mfma_f32_16x16x32_bf16((a),(b),(c),0,0,0)
// DS ops may not cross (keeps h write(t) -> read(t+1) order); all else schedules freely.
#define DS_FENCE()  __builtin_amdgcn_sched_barrier(0x7F)

template<int V> struct IC { static constexpr int value = V; };

union FragU { short8 s8; unsigned u[4]; uint4v u4; };

__device__ inline unsigned short f2bf(float f) {
    __bf16 h = (__bf16)f;
    return __builtin_bit_cast(unsigned short, h);
}
__device__ inline unsigned pk2(float lo, float hi) {
    return ((unsigned)f2bf(hi) << 16) | (unsigned)f2bf(lo);
}
// Involutive swizzle for the h buffer (same as R5).
__device__ inline unsigned swz(unsigned b) {
    return b ^ (((b >> 7) & 7u) << 4);
}

// A-operand weight fragments. k-slot for lane (q,st): k = kbase + i, kbase in {q*8, 32+q*8}.
__device__ inline short8 wfragX(const float* Wr, int kbase) {   // stride FAN row, zero pad k>=D_IN
    FragU f;
#pragma unroll
    for (int d = 0; d < 4; ++d) {
        int k0 = kbase + 2 * d, k1 = k0 + 1;
        float a = (k0 < D_IN) ? Wr[k0] : 0.0f;
        float b = (k1 < D_IN) ? Wr[k1] : 0.0f;
        f.u[d] = pk2(a, b);
    }
    return f.s8;
}
__device__ inline short8 wfragH(const float* Wr, int kbase) {   // stride FAN row (h part), full 64
    FragU f;
#pragma unroll
    for (int d = 0; d < 4; ++d) { int k0 = kbase + 2 * d; f.u[d] = pk2(Wr[k0], Wr[k0 + 1]); }
    return f.s8;
}
__device__ inline short8 wfrag64(const float* Wr, int kbase) {  // stride-64 row (ws matrices)
    FragU f;
#pragma unroll
    for (int d = 0; d < 4; ++d) { int k0 = kbase + 2 * d; f.u[d] = pk2(Wr[k0], Wr[k0 + 1]); }
    return f.s8;
}
__device__ inline short8 xfrag(const float* r) {
    FragU f;
#pragma unroll
    for (int d = 0; d < 4; ++d) f.u[d] = pk2(r[2 * d], r[2 * d + 1]);
    return f.s8;
}

struct XR { float a[8]; float b[8]; };
__device__ inline void loadx(XR& r, const float* xrow, int t, int q) {
    const float* p = xrow + t * D_IN;
#pragma unroll
    for (int i = 0; i < 8; ++i) r.a[i] = p[q * 8 + i];
    if (q == 3) {
        r.b[0] = p[56];
#pragma unroll
        for (int i = 1; i < 8; ++i) r.b[i] = 0.0f;
    } else {
#pragma unroll
        for (int i = 0; i < 8; ++i) r.b[i] = p[32 + q * 8 + i];
    }
}

__device__ inline void gld_lds16(const void* g, void* l) {
    __builtin_amdgcn_global_load_lds((const __attribute__((address_space(1))) void*)g,
                                     (__attribute__((address_space(3))) void*)l, 16, 0, 0);
}

// Read 32B (8 floats) from a 256B staged row with unit-XOR swizzle.
// A = alignment class of L (16/8/4). phys = (b&15) | (((b>>4)^st7)&15)<<4.
template<int A>
__device__ inline void ld32_swz(const char* row, int st7, int L, float* o) {
#pragma unroll
    for (int p = 0; p < 32 / A; ++p) {
        int b    = L + p * A;
        int phys = (b & 15) | ((((b >> 4) ^ st7) & 15) << 4);
        const char* ptr = row + phys;
        if constexpr (A == 16)      *(f32x4*)(o + 4 * p) = *(const f32x4*)ptr;
        else if constexpr (A == 8)  *(f32x2*)(o + 2 * p) = *(const f32x2*)ptr;
        else                        o[p] = *(const float*)ptr;
    }
}

// ---------- setup kernel: W2 = Wh*Wh, WX2 = Wh*Wx (64x64, cols>=57 zero), b2 = b + Wh*b ----------
__global__ __launch_bounds__(1024) void rnn_setup_kernel(
    const float* __restrict__ W_i2h, const float* __restrict__ b_i2h, float* __restrict__ ws)
{
    __shared__ float Wl[64 * FAN];
    int t = threadIdx.x;
    for (int idx = t; idx < 64 * FAN; idx += 1024) Wl[idx] = W_i2h[idx];
    __syncthreads();
    int i  = t >> 4;
    int c4 = t & 15;
#pragma unroll
    for (int jj = 0; jj < 4; ++jj) {
        int j = c4 * 4 + jj;
        float s2 = 0.0f, sx = 0.0f;
        for (int k = 0; k < 64; ++k) {
            float whik = Wl[i * FAN + D_IN + k];
            s2 += whik * Wl[k * FAN + D_IN + j];
            if (j < D_IN) sx += whik * Wl[k * FAN + j];
        }
        ws[i * 64 + j]        = s2;
        ws[4096 + i * 64 + j] = (j < D_IN) ? sx : 0.0f;
    }
    if (t < 64) {
        float s = b_i2h[t];
        for (int k = 0; k < 64; ++k) s += Wl[t * FAN + D_IN + k] * b_i2h[k];
        ws[8192 + t] = s;
    }
}

// ---------- main kernel ----------
__global__ __launch_bounds__(64, 1) void rnn_mfma_kernel(
    const float* __restrict__ x,
    const float* __restrict__ W_i2h,
    const float* __restrict__ b_i2h,
    const float* __restrict__ W_i2o,
    const float* __restrict__ b_i2o,
    const float* __restrict__ ws,
    float* __restrict__ out,
    int B)
{
    const int lane = threadIdx.x;
    const int st   = lane & 15;     // B col = seq within tile; A row = W row within tile
    const int q    = lane >> 4;     // K quarter
    const int seq0 = blockIdx.x * SEQ_PER_BLK;

    __shared__ __align__(16) float Xs[3][2][16][64];                 // 24 KB x stage (3 pair-bufs)
    __shared__ __align__(16) unsigned short Hs[SEQ_PER_BLK * HDIM];  // h, bf16, seq-major
    __shared__ __align__(16) float Hp[SEQ_PER_BLK][68];
    __shared__ int      Tl[SEQ_PER_BLK];
    __shared__ float    Lg[SEQ_PER_BLK][8];
    __shared__ unsigned Ms[SEQ_PER_BLK][4];

    char* HsB = (char*)Hs;

    // zero h_0
    {
        uint4v z = 0;
        *(uint4v*)(HsB + lane * 32)      = z;
        *(uint4v*)(HsB + lane * 32 + 16) = z;
    }

    const bool fullblk = (seq0 + SEQ_PER_BLK <= B);

    // ---- x staging machinery (fast path) ----
    const char* xb  = (const char*)x;
    const int   g   = lane >> 4;      // seq subgroup within staging inst
    const int   u0  = lane & 15;      // dest unit
    const char* gae = xb + (size_t)(seq0 + g) * XROW_B + (size_t)((u0 ^ g) << 4);
    const char* gao = xb + (size_t)(seq0 + g) * XROW_B + (size_t)((u0 ^ g ^ 4) << 4);

    auto STAGE = [&](int buf, int t0) {
        unsigned w0 = ((unsigned)(t0 * 228)) & ~15u;
        unsigned w1 = ((unsigned)((t0 + 1) * 228)) & ~15u;
        char* d0 = (char*)&Xs[buf][0][0][0];
        char* d1 = (char*)&Xs[buf][1][0][0];
#pragma unroll
        for (int i = 0; i < 4; ++i) {
            const char* gp = ((i & 1) ? gao : gae) + (size_t)i * 4 * XROW_B;
            gld_lds16(gp + w0, d0 + i * 1024);
            gld_lds16(gp + w1, d1 + i * 1024);
        }
    };

    // issue 3 pair-stages early: latency overlaps mask scan + weight-frag build
    if (fullblk) { STAGE(0, 0); STAGE(1, 2); STAGE(2, 4); }

    int seqL = seq0 + st; if (seqL >= B) seqL = B - 1;
    const float* xrow = x + (size_t)seqL * T_STEPS * D_IN;

    // validity masks
    {
        unsigned m = 0;
        const float* xq = xrow + (size_t)(q * 32) * D_IN;
#pragma unroll
        for (int i = 0; i < 32; ++i)
            m |= ((xq[(size_t)i * D_IN] != -1.0f) ? 1u : 0u) << i;
        Ms[st][q] = m;
    }
    const unsigned mk0 = Ms[st][0], mk1 = Ms[st][1];
    const unsigned mk2 = Ms[st][2], mk3 = Ms[st][3];
    const bool allv = __all((int)((mk0 & mk1 & mk2 & mk3) == 0xFFFFFFFFu));
    const bool fast = allv && fullblk;

    // resident weight fragments (fast loop set)
    short8 wxf[4][2], wx2f[4][2], w2f[4][2];
    f32x4  bias2v[4];
#pragma unroll
    for (int n = 0; n < 4; ++n) {
        const float* wr_ = W_i2h + (size_t)(16 * n + st) * FAN;
        wxf[n][0]  = wfragX(wr_, q * 8);
        wxf[n][1]  = wfragX(wr_, 32 + q * 8);
        const float* w2r = ws + (size_t)(16 * n + st) * 64;
        w2f[n][0]  = wfrag64(w2r, q * 8);
        w2f[n][1]  = wfrag64(w2r, 32 + q * 8);
        const float* wxr = ws + 4096 + (size_t)(16 * n + st) * 64;
        wx2f[n][0] = wfrag64(wxr, q * 8);
        wx2f[n][1] = wfrag64(wxr, 32 + q * 8);
#pragma unroll
        for (int j = 0; j < 4; ++j) bias2v[n][j] = ws[8192 + 16 * n + 4 * q + j];
    }

    // h LDS addressing (same as R5)
    const unsigned rb0 = swz((unsigned)(128 * st + 16 * q));
    const unsigned rb1 = swz((unsigned)(128 * st + 64 + 16 * q));
    unsigned wb[4];
#pragma unroll
    for (int n = 0; n < 4; ++n)
        wb[n] = swz((unsigned)(128 * st + 32 * n + 8 * q));

    f32x4 hpre[4];
#pragma unroll
    for (int n = 0; n < 4; ++n) hpre[n] = 0.0f;
    int tlv = -1;

    if (fast) {
        const int st7 = st & 7;
        const bool q3 = (q == 3);

        auto PAIR = [&](auto p0c, int buf, int t0) {
            constexpr int P0 = decltype(p0c)::value;       // 0 or 8
            constexpr int P1 = (P0 + 4) & 15;              // 4 or 12
            constexpr int A0 = (P0 % 16 == 0) ? 16 : 8;
            asm volatile("s_waitcnt vmcnt(16)" ::: "memory");   // pair's 8 gld_lds landed
            const char* row0 = (const char*)&Xs[buf][0][st][0];
            const char* row1 = (const char*)&Xs[buf][1][st][0];
            float a0[8], b0[8], a1[8], b1[8];
            ld32_swz<A0>(row0, st7, P0 + 32 * q,        a0);
            ld32_swz<A0>(row0, st7, P0 + 128 + 32 * q,  b0);
            ld32_swz<4 >(row1, st7, P1 + 32 * q,        a1);
            ld32_swz<4 >(row1, st7, P1 + 128 + 32 * q,  b1);
            FragU bh0, bh1;
            bh0.u4 = *(const uint4v*)(HsB + rb0);
            bh1.u4 = *(const uint4v*)(HsB + rb1);
            // prefetch pair t0+6 into the buffer just consumed
            int t3 = t0 + 6; if (t3 > 124) t3 = 124;
            STAGE(buf, t3);
            // zero the padded tail of the b-half for q==3 lanes
#pragma unroll
            for (int i = 1; i < 8; ++i) { b0[i] = q3 ? 0.0f : b0[i]; b1[i] = q3 ? 0.0f : b1[i]; }
            short8 x0a = xfrag(a0), x0b = xfrag(b0);
            short8 x1a = xfrag(a1), x1b = xfrag(b1);
            f32x4 acc[4];
#pragma unroll
            for (int n = 0; n < 4; ++n) {
                f32x4 c = bias2v[n];
                c = MFMA(wxf[n][0],  x1a, c);
                c = MFMA(wxf[n][1],  x1b, c);
                c = MFMA(wx2f[n][0], x0a, c);
                c = MFMA(wx2f[n][1], x0b, c);
                c = MFMA(w2f[n][0],  bh0.s8, c);
                c = MFMA(w2f[n][1],  bh1.s8, c);
                acc[n] = c;
            }
#pragma unroll
            for (int n = 0; n < 4; ++n) {
                uint2v w; w[0] = pk2(acc[n][0], acc[n][1]); w[1] = pk2(acc[n][2], acc[n][3]);
                *(uint2v*)(HsB + wb[n]) = w;
            }
            DS_FENCE();
        };

        int buf = 0;
        for (int db = 0; db < 31; ++db) {      // pairs 2db (pads 0/4), 2db+1 (pads 8/12)
            PAIR(IC<0>{}, buf, 4 * db);     buf = (buf == 2) ? 0 : buf + 1;
            PAIR(IC<8>{}, buf, 4 * db + 2); buf = (buf == 2) ? 0 : buf + 1;
        }
        PAIR(IC<0>{}, buf, 124);               // pair 62 -> h_125

        // peel t = 126: h_126 = Wh*h_125 + Wx*x_126 + b  (this is h_pre; h_127 is never used)
        short8 whf[4][2]; f32x4 biasv[4];
#pragma unroll
        for (int n = 0; n < 4; ++n) {
            const float* wr_ = W_i2h + (size_t)(16 * n + st) * FAN;
            whf[n][0] = wfragH(wr_ + D_IN, q * 8);
            whf[n][1] = wfragH(wr_ + D_IN, 32 + q * 8);
#pragma unroll
            for (int j = 0; j < 4; ++j) biasv[n][j] = b_i2h[16 * n + 4 * q + j];
        }
        XR rp; loadx(rp, xrow, 126, q);
        short8 pxa = xfrag(rp.a), pxb = xfrag(rp.b);
        FragU bh0, bh1;
        bh0.u4 = *(const uint4v*)(HsB + rb0);
        bh1.u4 = *(const uint4v*)(HsB + rb1);
#pragma unroll
        for (int n = 0; n < 4; ++n) {
            f32x4 c = biasv[n];
            c = MFMA(wxf[n][0], pxa, c);
            c = MFMA(wxf[n][1], pxb, c);
            c = MFMA(whf[n][0], bh0.s8, c);
            c = MFMA(whf[n][1], bh1.s8, c);
            hpre[n] = c;
        }
        tlv = 127;
    } else {
        // ---- general masked path (R5 structure, correct for any validity pattern) ----
        short8 whf[4][2]; f32x4 biasv[4];
#pragma unroll
        for (int n = 0; n < 4; ++n) {
            const float* wr_ = W_i2h + (size_t)(16 * n + st) * FAN;
            whf[n][0] = wfragH(wr_ + D_IN, q * 8);
            whf[n][1] = wfragH(wr_ + D_IN, 32 + q * 8);
#pragma unroll
            for (int j = 0; j < 4; ++j) biasv[n][j] = b_i2h[16 * n + 4 * q + j];
        }
        f32x4 hcur[4];
#pragma unroll
        for (int n = 0; n < 4; ++n) hcur[n] = 0.0f;

        XR r0, r1, r2, r3;
        loadx(r0, xrow, 0, q); loadx(r1, xrow, 1, q);
        loadx(r2, xrow, 2, q); loadx(r3, xrow, 3, q);

        auto STEPG = [&](XR& cur, int t, unsigned vbit) {
            FragU bh0, bh1;
            bh0.u4 = *(const uint4v*)(HsB + rb0);
            bh1.u4 = *(const uint4v*)(HsB + rb1);
            short8 bx0 = xfrag(cur.a);
            short8 bx1 = xfrag(cur.b);
            int tn = t + 4; if (tn > T_STEPS - 1) tn = T_STEPS - 1;
            loadx(cur, xrow, tn, q);
            f32x4 acc[4];
#pragma unroll
            for (int n = 0; n < 4; ++n) {
                f32x4 c = biasv[n];
                c = MFMA(wxf[n][0], bx0, c);
                c = MFMA(wxf[n][1], bx1, c);
                c = MFMA(whf[n][0], bh0.s8, c);
                c = MFMA(whf[n][1], bh1.s8, c);
                acc[n] = c;
            }
            bool v = vbit != 0;
#pragma unroll
            for (int n = 0; n < 4; ++n) {
#pragma unroll
                for (int j = 0; j < 4; ++j) {
                    float o = hcur[n][j];
                    hpre[n][j] = v ? o : hpre[n][j];
                    hcur[n][j] = v ? acc[n][j] : o;
                }
            }
#pragma unroll
            for (int n = 0; n < 4; ++n) {
                uint2v w; w[0] = pk2(hcur[n][0], hcur[n][1]); w[1] = pk2(hcur[n][2], hcur[n][3]);
                *(uint2v*)(HsB + wb[n]) = w;
            }
            DS_FENCE();
        };

        const unsigned mks[4] = { mk0, mk1, mk2, mk3 };
#pragma unroll 1
        for (int jb = 0; jb < 4; ++jb) {
            unsigned mw = mks[jb];
            int t0 = jb * 32;
#pragma unroll 1
            for (int i = 0; i < 32; i += 4) {
                STEPG(r0, t0 + i + 0, mw & 1u);  mw >>= 1;
                STEPG(r1, t0 + i + 1, mw & 1u);  mw >>= 1;
                STEPG(r2, t0 + i + 2, mw & 1u);  mw >>= 1;
                STEPG(r3, t0 + i + 3, mw & 1u);  mw >>= 1;
            }
        }
        if (mk3)      tlv = 127 - __builtin_clz(mk3);
        else if (mk2) tlv =  95 - __builtin_clz(mk2);
        else if (mk1) tlv =  63 - __builtin_clz(mk1);
        else if (mk0) tlv =  31 - __builtin_clz(mk0);
        else          tlv = -1;
    }

    // ---- epilogue ----
#pragma unroll
    for (int n = 0; n < 4; ++n)
        *(f32x4*)&Hp[st][16 * n + 4 * q] = hpre[n];
    if (lane < SEQ_PER_BLK) Tl[st] = tlv;
    __syncthreads();

    {
        int s = lane >> 2, p = lane & 3;
        int seq = seq0 + s;
        int t_l = Tl[s];
        float lgo0 = 0.0f, lgo1 = 0.0f;
        if (seq < B && t_l >= 0) {
            const float* xr = x + ((size_t)seq * T_STEPS + t_l) * D_IN;
            {
                const float* wo = W_i2o + p * FAN;
                float a = b_i2o[p];
                for (int k = 0; k < D_IN; ++k) a += xr[k] * wo[k];
                for (int k = 0; k < HDIM; ++k) a += Hp[s][k] * wo[D_IN + k];
                lgo0 = a;
            }
            if (p < 3) {
                const float* wo = W_i2o + (p + 4) * FAN;
                float a = b_i2o[p + 4];
                for (int k = 0; k < D_IN; ++k) a += xr[k] * wo[k];
                for (int k = 0; k < HDIM; ++k) a += Hp[s][k] * wo[D_IN + k];
                lgo1 = a;
            }
        }
        Lg[s][p] = lgo0;
        if (p < 3) Lg[s][p + 4] = lgo1;
    }
    __syncthreads();

    if (lane < SEQ_PER_BLK) {
        int s = lane, seq = seq0 + s;
        if (seq < B) {
            float* op = out + (size_t)seq * ODIM;
            if (Tl[s] < 0) {
#pragma unroll
                for (int o = 0; o < ODIM; ++o) op[o] = 0.0f;
            } else {
                float m = Lg[s][0];
#pragma unroll
                for (int o = 1; o < ODIM; ++o) m = fmaxf(m, Lg[s][o]);
                float sum = 0.0f;
#pragma unroll
                for (int o = 0; o < ODIM; ++o) sum += expf(Lg[s][o] - m);
                float lse = m + logf(sum);
#pragma unroll
                for (int o = 0; o < ODIM; ++o) op[o] = Lg[s][o] - lse;
            }
        }
    }
}

extern "C" void kernel_launch(void* const* d_in, const int* in_sizes, int n_in,
                              void* d_out, int out_size, void* d_ws, size_t ws_size,
                              hipStream_t stream)
{
    const float* x     = (const float*)d_in[0];
    const float* W_i2h = (const float*)d_in[1];
    const float* b_i2h = (const float*)d_in[2];
    const float* W_i2o = (const float*)d_in[3];
    const float* b_i2o = (const float*)d_in[4];
    float* out = (float*)d_out;
    float* ws  = (float*)d_ws;

    const int B = in_sizes[0] / (T_STEPS * D_IN);
    const int nblk = (B + SEQ_PER_BLK - 1) / SEQ_PER_BLK;

    hipLaunchKernelGGL(rnn_setup_kernel, dim3(1), dim3(1024), 0, stream, W_i2h, b_i2h, ws);
    hipLaunchKernelGGL(rnn_mfma_kernel, dim3(nblk), dim3(64), 0, stream,
                       x, W_i2h, b_i2h, W_i2o, b_i2o, (const float*)ws, out, B);
}